// Round 2
// baseline (245.337 us; speedup 1.0000x reference)
//
#include <hip/hip_runtime.h>

namespace {

constexpr int NROWS = 8192;  // N
constexpr int C = 1600;      // classes
constexpr int C4 = C / 4;    // 400 float4 per cls row
constexpr int L = 4;         // hierarchy levels
constexpr int K = 256;       // labels per level

// Extras-only chain: out[r][j] = in[r][j] + sum_t in[r][v[1+t]], t < v[0].
// v[0] in [0,4]. 16 B so one dwordx4 fetch.
struct alignas(16) Chain { short v[8]; };

// ---------------------------------------------------------------------------
// Build per-column extras chains (index data lives on device; tiny kernel).
// cls : level i writes tgt_i[k] = old[src_i[k]] + orig[tgt_i[k]]
// box : level i writes src_i[k] = old[tgt_i[k]] + orig[src_i[k]]
// Backward walk from the highest level that wrote column j; each hop emits
// one extra original-column term. Max hops = L = 4.
// ---------------------------------------------------------------------------
__global__ __launch_bounds__(256) void build_chains(
    const int* __restrict__ tgt, const int* __restrict__ src,
    Chain* __restrict__ ch_cls, Chain* __restrict__ ch_box) {
  __shared__ short tpos[L][C];  // tpos[i][c] = k if tgt[i][k]==c else -1
  __shared__ short spos[L][C];
  __shared__ short tg[L][K];
  __shared__ short sr[L][K];
  const int tid = threadIdx.x, nt = blockDim.x;

  for (int i = tid; i < L * C; i += nt) {
    (&tpos[0][0])[i] = -1;
    (&spos[0][0])[i] = -1;
  }
  __syncthreads();
  for (int i = tid; i < L * K; i += nt) {
    const int lvl = i / K, k = i % K;
    const int t = tgt[i], s = src[i];
    (&tg[0][0])[i] = (short)t;
    (&sr[0][0])[i] = (short)s;
    tpos[lvl][t] = (short)k;  // unique within a level (permutation slice)
    spos[lvl][s] = (short)k;
  }
  __syncthreads();

  for (int j = tid; j < C; j += nt) {
    {  // ---- cls chain ----
      Chain c;
      int cnt = 0, x = j, lvl = L - 1;
      for (;;) {
        int fi = -1, fk = -1;
        for (int i = lvl; i >= 0; --i) {
          const short p = tpos[i][x];
          if (p >= 0) { fi = i; fk = p; break; }
        }
        if (fi < 0) break;
        x = sr[fi][fk];
        lvl = fi - 1;
        c.v[1 + cnt++] = (short)x;
      }
      c.v[0] = (short)cnt;
      for (int t = cnt; t < 7; ++t) c.v[1 + t] = 0;
      ch_cls[j] = c;
    }
    {  // ---- box chain (src/tgt swapped) ----
      Chain c;
      int cnt = 0, x = j, lvl = L - 1;
      for (;;) {
        int fi = -1, fk = -1;
        for (int i = lvl; i >= 0; --i) {
          const short p = spos[i][x];
          if (p >= 0) { fi = i; fk = p; break; }
        }
        if (fi < 0) break;
        x = tg[fi][fk];
        lvl = fi - 1;
        c.v[1 + cnt++] = (short)x;
      }
      c.v[0] = (short)cnt;
      for (int t = cnt; t < 7; ++t) c.v[1 + t] = 0;
      ch_box[j] = c;
    }
  }
}

// ---------------------------------------------------------------------------
// Fused streaming apply. Base term is a coalesced pass-through copy
// (in4[tid] -> out4[tid]); extra terms are scattered loads inside the same
// row's 6.4-25.6 KB window, which is L1/L2-resident (base stream pulls every
// line exactly once from HBM). No LDS, no barriers.
//   blocks [0, BOX_BLOCKS)            : box, one float4 column per thread
//   blocks [BOX_BLOCKS, +CLS_BLOCKS)  : cls, four scalar columns per thread
// ---------------------------------------------------------------------------
constexpr int BOX_BLOCKS = NROWS * C / 256;   // 51200
constexpr int CLS_BLOCKS = NROWS * C4 / 256;  // 12800

__global__ __launch_bounds__(256) void apply_all(
    const float* __restrict__ logits, const float4* __restrict__ box,
    const Chain* __restrict__ ch_cls, const Chain* __restrict__ ch_box,
    float* __restrict__ out_cls, float4* __restrict__ out_box) {
  if (blockIdx.x < (unsigned)BOX_BLOCKS) {
    const int idx = blockIdx.x * 256 + threadIdx.x;  // row*C + col, < 13.1M
    const int col = idx % C;
    float4 s = box[idx];
    const Chain c = ch_box[col];
    const int n = c.v[0];
    if (n) {
      const int rowbase = idx - col;
      for (int t = 0; t < n; ++t) {
        const float4 a = box[rowbase + c.v[1 + t]];
        s.x += a.x; s.y += a.y; s.z += a.z; s.w += a.w;
      }
    }
    out_box[idx] = s;
  } else {
    const int idx = (blockIdx.x - BOX_BLOCKS) * 256 + threadIdx.x;  // row*C4+slot
    const int slot = idx % C4;
    const int rowbase = (idx - slot) * 4;  // row*C (scalar index)
    const float4 b = ((const float4*)logits)[idx];
    float s[4] = {b.x, b.y, b.z, b.w};
    const int j0 = slot * 4;
#pragma unroll
    for (int e = 0; e < 4; ++e) {
      const Chain c = ch_cls[j0 + e];
      const int n = c.v[0];
      for (int t = 0; t < n; ++t) s[e] += logits[rowbase + c.v[1 + t]];
    }
    float4 o;
    o.x = s[0]; o.y = s[1]; o.z = s[2]; o.w = s[3];
    ((float4*)out_cls)[idx] = o;
  }
}

}  // namespace

extern "C" void kernel_launch(void* const* d_in, const int* in_sizes, int n_in,
                              void* d_out, int out_size, void* d_ws, size_t ws_size,
                              hipStream_t stream) {
  const float* logits = (const float*)d_in[0];  // (N, C)
  const float* boxr   = (const float*)d_in[1];  // (N, 4C) == (N, C) float4
  const int*   tgt    = (const int*)d_in[2];    // (L, K)
  const int*   src    = (const int*)d_in[3];    // (L, K)

  float* out_cls = (float*)d_out;               // (N, C)
  float* out_box = out_cls + (size_t)NROWS * C; // (N, 4C)

  Chain* ch_cls = (Chain*)d_ws;                 // 25.6 KB
  Chain* ch_box = ch_cls + C;                   // 25.6 KB

  build_chains<<<1, 256, 0, stream>>>(tgt, src, ch_cls, ch_box);
  apply_all<<<BOX_BLOCKS + CLS_BLOCKS, 256, 0, stream>>>(
      logits, (const float4*)boxr, ch_cls, ch_box, out_cls, (float4*)out_box);
}

// Round 3
// 138.030 us; speedup vs baseline: 1.7774x; 1.7774x over previous
//
#include <hip/hip_runtime.h>

namespace {

constexpr int NROWS = 8192;  // N
constexpr int C = 1600;      // classes
constexpr int C4 = C / 4;    // 400 float4 per cls row
constexpr int L = 4;         // hierarchy levels
constexpr int K = 256;       // labels per level

// Packed chain: out[j] = in[j] + sum of n extra original columns.
// x = n | idx0<<4 | idx1<<15 ; y = idx2 | idx3<<11   (indices < 2048)
constexpr int NB_BOX = 2048;  // 4 box rows per block, sequential
constexpr int NB_CLS = 512;   // 16 cls rows per block, 4 groups of 4

// ---------------------------------------------------------------------------
// Build per-column extras chains (packed). Same walk as R1/R2 (verified).
// cls : level i writes tgt_i[k] = old[src_i[k]] + orig[tgt_i[k]]
// box : level i writes src_i[k] = old[tgt_i[k]] + orig[src_i[k]]
// ---------------------------------------------------------------------------
__global__ __launch_bounds__(256) void build_chains(
    const int* __restrict__ tgt, const int* __restrict__ src,
    uint2* __restrict__ pc_cls, uint2* __restrict__ pc_box) {
  __shared__ short tpos[L][C];
  __shared__ short spos[L][C];
  __shared__ short tg[L][K];
  __shared__ short sr[L][K];
  const int tid = threadIdx.x, nt = blockDim.x;

  for (int i = tid; i < L * C; i += nt) {
    (&tpos[0][0])[i] = -1;
    (&spos[0][0])[i] = -1;
  }
  __syncthreads();
  for (int i = tid; i < L * K; i += nt) {
    const int lvl = i / K, k = i % K;
    const int t = tgt[i], s = src[i];
    (&tg[0][0])[i] = (short)t;
    (&sr[0][0])[i] = (short)s;
    tpos[lvl][t] = (short)k;  // unique within a level (permutation slice)
    spos[lvl][s] = (short)k;
  }
  __syncthreads();

  for (int j = tid; j < C; j += nt) {
    {  // ---- cls ----
      int idx[4] = {0, 0, 0, 0};
      int cnt = 0, x = j, lvl = L - 1;
      for (;;) {
        int fi = -1, fk = -1;
        for (int i = lvl; i >= 0; --i) {
          const short p = tpos[i][x];
          if (p >= 0) { fi = i; fk = p; break; }
        }
        if (fi < 0) break;
        x = sr[fi][fk];
        lvl = fi - 1;
        idx[cnt++] = x;
      }
      uint2 p;
      p.x = (unsigned)cnt | ((unsigned)idx[0] << 4) | ((unsigned)idx[1] << 15);
      p.y = (unsigned)idx[2] | ((unsigned)idx[3] << 11);
      pc_cls[j] = p;
    }
    {  // ---- box (src/tgt swapped) ----
      int idx[4] = {0, 0, 0, 0};
      int cnt = 0, x = j, lvl = L - 1;
      for (;;) {
        int fi = -1, fk = -1;
        for (int i = lvl; i >= 0; --i) {
          const short p = spos[i][x];
          if (p >= 0) { fi = i; fk = p; break; }
        }
        if (fi < 0) break;
        x = tg[fi][fk];
        lvl = fi - 1;
        idx[cnt++] = x;
      }
      uint2 p;
      p.x = (unsigned)cnt | ((unsigned)idx[0] << 4) | ((unsigned)idx[1] << 15);
      p.y = (unsigned)idx[2] | ((unsigned)idx[3] << 11);
      pc_box[j] = p;
    }
  }
}

__device__ __forceinline__ void add4(float4& s, const float4 a) {
  s.x += a.x; s.y += a.y; s.z += a.z; s.w += a.w;
}

// ---------------------------------------------------------------------------
// Fused apply. Persistent blocks; chains live in VGPRs for the whole block;
// the staging register doubles as the base term (LDS only serves gathers).
//   blocks [0, NB_BOX)  : 4 box rows each (float4 columns, 25.6 KB LDS row)
//   blocks [NB_BOX, ..) : 16 cls rows each in 4 groups of 4 (scalar gathers)
// ---------------------------------------------------------------------------
__global__ __launch_bounds__(256) void apply_fused(
    const float* __restrict__ logits, const float4* __restrict__ box,
    const uint2* __restrict__ pc_cls, const uint2* __restrict__ pc_box,
    float* __restrict__ out_cls, float4* __restrict__ out_box) {
  __shared__ float4 smem[C];  // 25.6 KB, aliased by both halves
  const int tid = threadIdx.x;

  if (blockIdx.x < (unsigned)NB_BOX) {
    // ---------------- box ----------------
    uint2 ch[7];
#pragma unroll
    for (int k = 0; k < 7; ++k) {
      const int col = tid + k * 256;
      if (col < C) ch[k] = pc_box[col];
    }
    const int r0 = blockIdx.x * 4;
#pragma unroll 1
    for (int r = 0; r < 4; ++r) {
      const float4* brow = box + (size_t)(r0 + r) * C;
      float4 v[7];
#pragma unroll
      for (int k = 0; k < 7; ++k) {
        const int col = tid + k * 256;
        if (col < C) { v[k] = brow[col]; smem[col] = v[k]; }
      }
      __syncthreads();
      float4* orow = out_box + (size_t)(r0 + r) * C;
#pragma unroll
      for (int k = 0; k < 7; ++k) {
        const int col = tid + k * 256;
        if (col < C) {
          float4 s = v[k];
          const uint2 p = ch[k];
          const int n = p.x & 0xF;
          if (n > 0) add4(s, smem[(p.x >> 4) & 0x7FF]);
          if (n > 1) add4(s, smem[(p.x >> 15) & 0x7FF]);
          if (n > 2) add4(s, smem[p.y & 0x7FF]);
          if (n > 3) add4(s, smem[(p.y >> 11) & 0x7FF]);
          orow[col] = s;
        }
      }
      __syncthreads();  // protect smem before next row's overwrite
    }
  } else {
    // ---------------- cls ----------------
    const int blk = blockIdx.x - NB_BOX;
    float* rows = (float*)smem;  // [4][C] floats = 25.6 KB
    uint2 ch[2][4];
#pragma unroll
    for (int k = 0; k < 2; ++k) {
      const int s = tid + k * 256;
      if (s < C4) {
#pragma unroll
        for (int e = 0; e < 4; ++e) ch[k][e] = pc_cls[4 * s + e];
      }
    }
    const float4* lg4 = (const float4*)logits;
    float4* oc4 = (float4*)out_cls;
#pragma unroll 1
    for (int g = 0; g < 4; ++g) {
      const int r0 = blk * 16 + g * 4;
      float4 v[2][4];
#pragma unroll
      for (int k = 0; k < 2; ++k) {
        const int s = tid + k * 256;
        if (s < C4) {
#pragma unroll
          for (int r = 0; r < 4; ++r) {
            const float4 t = lg4[(size_t)(r0 + r) * C4 + s];
            v[k][r] = t;
            ((float4*)(rows + r * C))[s] = t;
          }
        }
      }
      __syncthreads();
#pragma unroll
      for (int k = 0; k < 2; ++k) {
        const int s = tid + k * 256;
        if (s < C4) {
#pragma unroll
          for (int r = 0; r < 4; ++r) {
            float4 sv = v[k][r];
            const float* rw = rows + r * C;
            {
              const uint2 p = ch[k][0];
              const int n = p.x & 0xF;
              if (n > 0) sv.x += rw[(p.x >> 4) & 0x7FF];
              if (n > 1) sv.x += rw[(p.x >> 15) & 0x7FF];
              if (n > 2) sv.x += rw[p.y & 0x7FF];
              if (n > 3) sv.x += rw[(p.y >> 11) & 0x7FF];
            }
            {
              const uint2 p = ch[k][1];
              const int n = p.x & 0xF;
              if (n > 0) sv.y += rw[(p.x >> 4) & 0x7FF];
              if (n > 1) sv.y += rw[(p.x >> 15) & 0x7FF];
              if (n > 2) sv.y += rw[p.y & 0x7FF];
              if (n > 3) sv.y += rw[(p.y >> 11) & 0x7FF];
            }
            {
              const uint2 p = ch[k][2];
              const int n = p.x & 0xF;
              if (n > 0) sv.z += rw[(p.x >> 4) & 0x7FF];
              if (n > 1) sv.z += rw[(p.x >> 15) & 0x7FF];
              if (n > 2) sv.z += rw[p.y & 0x7FF];
              if (n > 3) sv.z += rw[(p.y >> 11) & 0x7FF];
            }
            {
              const uint2 p = ch[k][3];
              const int n = p.x & 0xF;
              if (n > 0) sv.w += rw[(p.x >> 4) & 0x7FF];
              if (n > 1) sv.w += rw[(p.x >> 15) & 0x7FF];
              if (n > 2) sv.w += rw[p.y & 0x7FF];
              if (n > 3) sv.w += rw[(p.y >> 11) & 0x7FF];
            }
            oc4[(size_t)(r0 + r) * C4 + s] = sv;
          }
        }
      }
      __syncthreads();
    }
  }
}

}  // namespace

extern "C" void kernel_launch(void* const* d_in, const int* in_sizes, int n_in,
                              void* d_out, int out_size, void* d_ws, size_t ws_size,
                              hipStream_t stream) {
  const float* logits = (const float*)d_in[0];  // (N, C)
  const float* boxr   = (const float*)d_in[1];  // (N, 4C) == (N, C) float4
  const int*   tgt    = (const int*)d_in[2];    // (L, K)
  const int*   src    = (const int*)d_in[3];    // (L, K)

  float* out_cls = (float*)d_out;                // (N, C)
  float* out_box = out_cls + (size_t)NROWS * C;  // (N, 4C)

  uint2* pc_cls = (uint2*)d_ws;  // 12.8 KB
  uint2* pc_box = pc_cls + C;    // 12.8 KB

  build_chains<<<1, 256, 0, stream>>>(tgt, src, pc_cls, pc_box);
  apply_fused<<<NB_BOX + NB_CLS, 256, 0, stream>>>(
      logits, (const float4*)boxr, pc_cls, pc_box, out_cls, (float4*)out_box);
}

// Round 4
// 135.695 us; speedup vs baseline: 1.8080x; 1.0172x over previous
//
#include <hip/hip_runtime.h>

namespace {

constexpr int NROWS = 8192;  // N
constexpr int C = 1600;      // classes
constexpr int L = 4;         // hierarchy levels
constexpr int K = 256;       // labels per level

constexpr int TB = 320;          // 5 waves; 1600 float4 / 320 = 5 per thread
constexpr int CPB = 8;           // chunks per block
constexpr int BOX_BLOCKS = 1024; // 8192 rows / 8
constexpr int CLS_BLOCKS = 256;  // 2048 groups / 8

// Packed extras chain for column j: out[j] = (reversed-sum of extras) + in[j]
// x = n | idx0<<4 | idx1<<15 ; y = idx2 | idx3<<11   (indices < 2048)

// ---------------------------------------------------------------------------
// Build per-column extras chains (verified walk from R1-R3; now 1024 threads).
// cls : level i writes tgt_i[k] = old[src_i[k]] + orig[tgt_i[k]]
// box : level i writes src_i[k] = old[tgt_i[k]] + orig[src_i[k]]
// ---------------------------------------------------------------------------
__global__ __launch_bounds__(1024) void build_chains(
    const int* __restrict__ tgt, const int* __restrict__ src,
    uint2* __restrict__ pc_cls, uint2* __restrict__ pc_box) {
  __shared__ short tpos[L][C];
  __shared__ short spos[L][C];
  __shared__ short tg[L][K];
  __shared__ short sr[L][K];
  const int tid = threadIdx.x, nt = blockDim.x;

  for (int i = tid; i < L * C; i += nt) {
    (&tpos[0][0])[i] = -1;
    (&spos[0][0])[i] = -1;
  }
  __syncthreads();
  for (int i = tid; i < L * K; i += nt) {
    const int lvl = i / K, k = i % K;
    const int t = tgt[i], s = src[i];
    (&tg[0][0])[i] = (short)t;
    (&sr[0][0])[i] = (short)s;
    tpos[lvl][t] = (short)k;  // unique within a level (permutation slice)
    spos[lvl][s] = (short)k;
  }
  __syncthreads();

  for (int j = tid; j < C; j += nt) {
    {  // ---- cls ----
      int idx[4] = {0, 0, 0, 0};
      int cnt = 0, x = j, lvl = L - 1;
      for (;;) {
        int fi = -1, fk = -1;
        for (int i = lvl; i >= 0; --i) {
          const short p = tpos[i][x];
          if (p >= 0) { fi = i; fk = p; break; }
        }
        if (fi < 0) break;
        x = sr[fi][fk];
        lvl = fi - 1;
        idx[cnt++] = x;
      }
      uint2 p;
      p.x = (unsigned)cnt | ((unsigned)idx[0] << 4) | ((unsigned)idx[1] << 15);
      p.y = (unsigned)idx[2] | ((unsigned)idx[3] << 11);
      pc_cls[j] = p;
    }
    {  // ---- box (src/tgt swapped) ----
      int idx[4] = {0, 0, 0, 0};
      int cnt = 0, x = j, lvl = L - 1;
      for (;;) {
        int fi = -1, fk = -1;
        for (int i = lvl; i >= 0; --i) {
          const short p = spos[i][x];
          if (p >= 0) { fi = i; fk = p; break; }
        }
        if (fi < 0) break;
        x = tg[fi][fk];
        lvl = fi - 1;
        idx[cnt++] = x;
      }
      uint2 p;
      p.x = (unsigned)cnt | ((unsigned)idx[0] << 4) | ((unsigned)idx[1] << 15);
      p.y = (unsigned)idx[2] | ((unsigned)idx[3] << 11);
      pc_box[j] = p;
    }
  }
}

__device__ __forceinline__ void gload16(const void* g, void* l) {
  __builtin_amdgcn_global_load_lds(
      (const __attribute__((address_space(1))) unsigned int*)g,
      (__attribute__((address_space(3))) unsigned int*)l, 16, 0, 0);
}

__device__ __forceinline__ void add4(float4& s, const float4 a) {
  s.x += a.x; s.y += a.y; s.z += a.z; s.w += a.w;
}

// ---------------------------------------------------------------------------
// Fused apply. Double-buffered 25.6 KB chunks staged with async
// global_load_lds (16 B/lane); next chunk's loads are in flight during the
// current chunk's gather+store; one vmcnt(0)+barrier per chunk.
//   blocks [0, BOX_BLOCKS)  : chunk = 1 box row   (1600 float4)
//   blocks [BOX_BLOCKS, ..) : chunk = 4 cls rows  (1600 float4)
// Extras accumulate deepest-first, base added last == reference association
// order (bit-exact).
// ---------------------------------------------------------------------------
__global__ __launch_bounds__(TB) void apply_fused(
    const float* __restrict__ logits, const float4* __restrict__ box,
    const uint2* __restrict__ pc_cls, const uint2* __restrict__ pc_box,
    float* __restrict__ out_cls, float4* __restrict__ out_box) {
  __shared__ float4 smem[2][C];  // 51.2 KB
  const int tid = threadIdx.x;
  const int wave = tid >> 6, lane = tid & 63;

  // stage one 25.6 KB contiguous chunk: 5 gload16 per wave, uniform
  auto stage = [&](int buf, const void* src) {
#pragma unroll
    for (int k = 0; k < 5; ++k) {
      const int u = k * 5 + wave;  // 25 KB-units
      gload16((const char*)src + u * 1024 + lane * 16,
              (char*)&smem[buf][0] + u * 1024);
    }
  };

  if (blockIdx.x < (unsigned)BOX_BLOCKS) {
    // ---------------- box: one row per chunk ----------------
    const int r0 = blockIdx.x * CPB;
    uint2 ch[5];
    stage(0, box + (size_t)r0 * C);
#pragma unroll
    for (int k = 0; k < 5; ++k) ch[k] = pc_box[tid + k * TB];
    asm volatile("s_waitcnt vmcnt(0)" ::: "memory");
    __syncthreads();
    int cur = 0;
#pragma unroll 1
    for (int c = 0; c < CPB; ++c) {
      if (c + 1 < CPB) stage(cur ^ 1, box + (size_t)(r0 + c + 1) * C);
      const float4* row = smem[cur];
      float4* orow = out_box + (size_t)(r0 + c) * C;
#pragma unroll
      for (int k = 0; k < 5; ++k) {
        const int col = tid + k * TB;
        const uint2 p = ch[k];
        const int n = p.x & 0xF;
        float4 a = make_float4(0.f, 0.f, 0.f, 0.f);
        if (n > 3) add4(a, row[(p.y >> 11) & 0x7FF]);
        if (n > 2) add4(a, row[p.y & 0x7FF]);
        if (n > 1) add4(a, row[(p.x >> 15) & 0x7FF]);
        if (n > 0) add4(a, row[(p.x >> 4) & 0x7FF]);
        add4(a, row[col]);  // base last = reference order
        orow[col] = a;
      }
      asm volatile("s_waitcnt vmcnt(0)" ::: "memory");
      __syncthreads();
      cur ^= 1;
    }
  } else {
    // ---------------- cls: four rows per chunk ----------------
    const int g0 = (blockIdx.x - BOX_BLOCKS) * CPB;
    uint2 ch[5][4];
    stage(0, logits + (size_t)g0 * (4 * C));
#pragma unroll
    for (int k = 0; k < 5; ++k) {
      const int c4 = (tid + k * TB) % 400;
#pragma unroll
      for (int e = 0; e < 4; ++e) ch[k][e] = pc_cls[c4 * 4 + e];
    }
    asm volatile("s_waitcnt vmcnt(0)" ::: "memory");
    __syncthreads();
    int cur = 0;
#pragma unroll 1
    for (int c = 0; c < CPB; ++c) {
      if (c + 1 < CPB) stage(cur ^ 1, logits + (size_t)(g0 + c + 1) * (4 * C));
      const float* rows = (const float*)smem[cur];          // [4][1600]
      float4* o4 = (float4*)out_cls + (size_t)(g0 + c) * C;  // [4][400] f4
#pragma unroll
      for (int k = 0; k < 5; ++k) {
        const int s4 = tid + k * TB;       // slot in chunk, r*400+c4
        const int r = s4 / 400;
        const int c4 = s4 - r * 400;
        const float* rw = rows + r * C;
        float4 v = ((const float4*)rw)[c4];
        float acc;
        {
          const uint2 p = ch[k][0]; const int n = p.x & 0xF; acc = 0.f;
          if (n > 3) acc += rw[(p.y >> 11) & 0x7FF];
          if (n > 2) acc += rw[p.y & 0x7FF];
          if (n > 1) acc += rw[(p.x >> 15) & 0x7FF];
          if (n > 0) acc += rw[(p.x >> 4) & 0x7FF];
          v.x = acc + v.x;
        }
        {
          const uint2 p = ch[k][1]; const int n = p.x & 0xF; acc = 0.f;
          if (n > 3) acc += rw[(p.y >> 11) & 0x7FF];
          if (n > 2) acc += rw[p.y & 0x7FF];
          if (n > 1) acc += rw[(p.x >> 15) & 0x7FF];
          if (n > 0) acc += rw[(p.x >> 4) & 0x7FF];
          v.y = acc + v.y;
        }
        {
          const uint2 p = ch[k][2]; const int n = p.x & 0xF; acc = 0.f;
          if (n > 3) acc += rw[(p.y >> 11) & 0x7FF];
          if (n > 2) acc += rw[p.y & 0x7FF];
          if (n > 1) acc += rw[(p.x >> 15) & 0x7FF];
          if (n > 0) acc += rw[(p.x >> 4) & 0x7FF];
          v.z = acc + v.z;
        }
        {
          const uint2 p = ch[k][3]; const int n = p.x & 0xF; acc = 0.f;
          if (n > 3) acc += rw[(p.y >> 11) & 0x7FF];
          if (n > 2) acc += rw[p.y & 0x7FF];
          if (n > 1) acc += rw[(p.x >> 15) & 0x7FF];
          if (n > 0) acc += rw[(p.x >> 4) & 0x7FF];
          v.w = acc + v.w;
        }
        o4[s4] = v;
      }
      asm volatile("s_waitcnt vmcnt(0)" ::: "memory");
      __syncthreads();
      cur ^= 1;
    }
  }
}

}  // namespace

extern "C" void kernel_launch(void* const* d_in, const int* in_sizes, int n_in,
                              void* d_out, int out_size, void* d_ws, size_t ws_size,
                              hipStream_t stream) {
  const float* logits = (const float*)d_in[0];  // (N, C)
  const float* boxr   = (const float*)d_in[1];  // (N, 4C) == (N, C) float4
  const int*   tgt    = (const int*)d_in[2];    // (L, K)
  const int*   src    = (const int*)d_in[3];    // (L, K)

  float* out_cls = (float*)d_out;                // (N, C)
  float* out_box = out_cls + (size_t)NROWS * C;  // (N, 4C)

  uint2* pc_cls = (uint2*)d_ws;  // 12.8 KB
  uint2* pc_box = pc_cls + C;    // 12.8 KB

  build_chains<<<1, 1024, 0, stream>>>(tgt, src, pc_cls, pc_box);
  apply_fused<<<BOX_BLOCKS + CLS_BLOCKS, TB, 0, stream>>>(
      logits, (const float4*)boxr, pc_cls, pc_box, out_cls, (float4*)out_box);
}